// Round 11
// baseline (173.724 us; speedup 1.0000x reference)
//
#include <hip/hip_runtime.h>
#include <hip/hip_bf16.h>

#define BB 128
#define NN 36
#define DD 1024
#define HH 16
#define ROWS (BB*NN)          // 4608

typedef __attribute__((ext_vector_type(8))) __bf16 bf16x8;
typedef __attribute__((ext_vector_type(4))) float f32x4;
typedef __attribute__((ext_vector_type(4))) unsigned short us4;

__device__ inline unsigned short f2bf(float f) {
    __hip_bfloat16 h = __float2bfloat16(f);
    return *reinterpret_cast<unsigned short*>(&h);
}

// ---------------- prep: roi->bf16, W->bf16, extra  (one launch) ----------------
// grid: [0,4608) roi cvt | [4608,7680) weight cvt | [7680,8328) extra
__global__ __launch_bounds__(256) void prep_kernel(const float* __restrict__ roi,
                                                   const float* __restrict__ Wq,
                                                   const float* __restrict__ Wk,
                                                   const float* __restrict__ Wout,
                                                   const float* __restrict__ pe,
                                                   const float* __restrict__ Wpos,
                                                   const float* __restrict__ bpos,
                                                   const int* __restrict__ adj,
                                                   const float* __restrict__ lbl,
                                                   unsigned short* __restrict__ roi_bf,
                                                   unsigned short* __restrict__ Wcat_bf,
                                                   float* __restrict__ extra) {
    const int bid = blockIdx.x, tid = threadIdx.x;
    if (bid < 4608) {
        int i = bid * 256 + tid;
        f32x4 v = ((const f32x4*)roi)[i];
        us4 o;
        o.x = f2bf(v[0]); o.y = f2bf(v[1]); o.z = f2bf(v[2]); o.w = f2bf(v[3]);
        ((us4*)roi_bf)[i] = o;
        return;
    }
    if (bid < 7680) {
        int wb = bid - 4608;
        int sel = wb >> 10;
        const float* src = sel == 0 ? Wq : (sel == 1 ? Wk : Wout);
        int i = (wb & 1023) * 256 + tid;
        f32x4 v = ((const f32x4*)src)[i];
        us4 o;
        o.x = f2bf(v[0]); o.y = f2bf(v[1]); o.z = f2bf(v[2]); o.w = f2bf(v[3]);
        ((us4*)(Wcat_bf + (size_t)sel * DD * DD))[i] = o;
        return;
    }
    __shared__ __align__(16) float wps[HH * 64];
    __shared__ float bps[HH];
    for (int i = tid; i < HH * 64; i += 256) wps[i] = Wpos[i];
    if (tid < HH) bps[tid] = bpos[tid];
    __syncthreads();

    int idx = (bid - 7680) * 256 + tid;           // one (b,n,m); 165888 total
    f32x4 pr[16];
    const f32x4* pv = (const f32x4*)(pe + (size_t)idx * 64);
#pragma unroll
    for (int j = 0; j < 16; j++) pr[j] = pv[j];
    int a = adj[idx];
    float add = lbl[idx] + (a > 0 ? 0.f : -9e15f);
    int b = idx / 1296, nm = idx % 1296;
    size_t obase = (size_t)b * (16 * 1296) + nm;
    for (int hh = 0; hh < 16; hh++) {
        const f32x4* wv = (const f32x4*)(wps + hh * 64);
        f32x4 acc4 = {0.f, 0.f, 0.f, 0.f};
#pragma unroll
        for (int j = 0; j < 16; j++) acc4 += pr[j] * wv[j];
        float d = acc4[0] + acc4[1] + acc4[2] + acc4[3] + bps[hh];
        d = fmaxf(d, 0.f);
        d = __logf(fmaxf(d, 1e-6f));
        extra[obase + (size_t)hh * 1296] = d + add;
    }
}

// ---------------- fused GEMM + attention: one block per (4-batch group, head) ----------------
// M=144 (4 batches x 36), N=192 ([q|k|vw] head slices), K=1024, BK=64, XOR-swizzled LDS,
// grid 32x16=512. K-loop software pipeline: register prefetch issued AFTER barrier #1 so
// the vmcnt(0) drain at barrier #2 overlaps the whole compute phase (loads in flight
// during MFMA). ds_write of rbuf before barrier #1 satisfies the WAR on rbuf.
__global__ __launch_bounds__(256, 2) void fused_kernel(const unsigned short* __restrict__ A,
                                                       const unsigned short* __restrict__ Wc,
                                                       const float* __restrict__ bq,
                                                       const float* __restrict__ bk,
                                                       const float* __restrict__ extra,
                                                       const float* __restrict__ bout,
                                                       float* __restrict__ out) {
    __shared__ __align__(16) unsigned short pool[21504];   // 43008 B
    const int tid  = threadIdx.x;
    const int wave = tid >> 6, lane = tid & 63;
    const int quad = lane >> 4, l16 = lane & 15;
    const int h  = blockIdx.x & 15;
    const int bg = blockIdx.x >> 4;            // 0..31, 4 batches each
    const int row0 = bg * 144;

    unsigned short* As = pool;                 // [144][64] sw (18 slots x 512)
    unsigned short* Bs = pool + 9216;          // [192][64] sw (24 slots x 512)

    // hoisted staging addresses: slot j = wave + 4*i, i = 0..10 (j<42 valid)
    const f32x4* gsrc[11];
    f32x4* ldst[11];
#pragma unroll
    for (int i = 0; i < 11; i++) {
        int j = wave + 4 * i;
        int c = j * 64 + lane;
        if (j < 18) {                          // A: 1152 chunks (144 rows x 8)
            int row = c >> 3;
            int col = ((c & 7) ^ (row & 7)) * 8;
            gsrc[i] = (const f32x4*)(A + (size_t)(row0 + row) * DD + col);
            ldst[i] = (f32x4*)(As + j * 512 + lane * 8);
        } else {                               // B: 1536 chunks (192 rows x 8)
            int cb = c - 1152;
            int row = cb >> 3;
            if (row > 191) row = 191;          // clamp unused slots (wave>=2, i==10)
            int sec = row >> 6;
            int wrow = sec * DD + h * 64 + (row & 63);
            int col = ((cb & 7) ^ (row & 7)) * 8;
            gsrc[i] = (const f32x4*)(Wc + (size_t)wrow * DD + col);
            ldst[i] = (f32x4*)(Bs + (j - 18) * 512 + lane * 8);
        }
    }

    f32x4 acc[9][3] = {};                      // rows rt*16, wave's 48-col slice ct*16
    f32x4 rbuf[11];

    // prologue: tile 0 into regs
#pragma unroll
    for (int i = 0; i < 11; i++)
        if (i < 10 || wave < 2)
            rbuf[i] = gsrc[i][0];

#pragma unroll
    for (int k0i = 0; k0i < 16; k0i++) {
        // stage current tile regs -> LDS (waits the in-flight loads naturally)
#pragma unroll
        for (int i = 0; i < 11; i++)
            if (i < 10 || wave < 2)
                *ldst[i] = rbuf[i];
        __syncthreads();   // no VM in flight here: drain is lgkm-only (cheap)

        // issue next-tile prefetch NOW: in flight across the whole compute phase;
        // the vmcnt(0) at the closing __syncthreads overlaps with MFMA below.
        if (k0i < 15) {
#pragma unroll
            for (int i = 0; i < 11; i++)
                if (i < 10 || wave < 2)
                    rbuf[i] = gsrc[i][(k0i + 1) * 8];   // +64 shorts = 8 f32x4
        }

#pragma unroll
        for (int ks = 0; ks < 2; ks++) {
            int kch = ks * 4 + quad;
            bf16x8 bfv[3], afv[9];
#pragma unroll
            for (int ct = 0; ct < 3; ct++) {
                int rowb = wave * 48 + ct * 16 + l16;
                bfv[ct] = *(const bf16x8*)&Bs[rowb * 64 + ((kch ^ (rowb & 7)) * 8)];
            }
#pragma unroll
            for (int rt = 0; rt < 9; rt++) {
                int rowa = rt * 16 + l16;
                afv[rt] = *(const bf16x8*)&As[rowa * 64 + ((kch ^ (rowa & 7)) * 8)];
            }
#pragma unroll
            for (int rt = 0; rt < 9; rt++)
#pragma unroll
                for (int ct = 0; ct < 3; ct++)
                    acc[rt][ct] = __builtin_amdgcn_mfma_f32_16x16x32_bf16(afv[rt], bfv[ct], acc[rt][ct], 0, 0, 0);
        }
        __syncthreads();
    }

    // ---------------- prefetch extra + bout (hidden under spill + QK) ----------------
    const int bat = wave;
    const float* exb = extra + ((size_t)((bg * 4 + bat) * 16 + h)) * 1296;
    float exv[3][4][3];
#pragma unroll
    for (int mt = 0; mt < 3; mt++)
#pragma unroll
        for (int r = 0; r < 4; r++) {
            int row = mt * 16 + quad * 4 + r;
#pragma unroll
            for (int nt = 0; nt < 3; nt++) {
                int col = nt * 16 + l16;
                exv[mt][r][nt] = (row < 36 && col < 36) ? exb[row * 36 + col] : 0.f;
            }
        }
    float bo[4];
#pragma unroll
    for (int nt = 0; nt < 4; nt++) bo[nt] = bout[h * 64 + nt * 16 + l16];

    // ---------------- phase 1: spill q,k (stride 72) ----------------
    unsigned short* qL = pool;                 // [144][72]
    unsigned short* kL = pool + 10368;         // [144][72]
#pragma unroll
    for (int ct = 0; ct < 3; ct++) {
        int g = wave * 48 + ct * 16 + l16;
        int sec = g >> 6, e = g & 63;
        if (sec < 2) {
            unsigned short* dst = (sec == 0) ? qL : kL;
            float bias = (sec == 0) ? bq[h * 64 + e] : bk[h * 64 + e];
#pragma unroll
            for (int rt = 0; rt < 9; rt++)
#pragma unroll
                for (int r = 0; r < 4; r++) {
                    int row = rt * 16 + quad * 4 + r;
                    dst[row * 72 + e] = f2bf(acc[rt][ct][r] + bias);
                }
        }
    }
    __syncthreads();

    // ---------------- phase 2: QK^T per wave (batch = wave) ----------------
    const unsigned short* qB = qL + bat * 36 * 72;
    const unsigned short* kB = kL + bat * 36 * 72;
    int rq[3];
#pragma unroll
    for (int t = 0; t < 3; t++) { int rr = t * 16 + l16; rq[t] = rr < 36 ? rr : 35; }

    f32x4 aff[3][3] = {};
#pragma unroll
    for (int ks = 0; ks < 2; ks++) {
        bf16x8 afr[3], bfr[3];
#pragma unroll
        for (int t = 0; t < 3; t++) afr[t] = *(const bf16x8*)&qB[rq[t] * 72 + ks * 32 + quad * 8];
#pragma unroll
        for (int t = 0; t < 3; t++) bfr[t] = *(const bf16x8*)&kB[rq[t] * 72 + ks * 32 + quad * 8];
#pragma unroll
        for (int mt = 0; mt < 3; mt++)
#pragma unroll
            for (int nt = 0; nt < 3; nt++)
                aff[mt][nt] = __builtin_amdgcn_mfma_f32_16x16x32_bf16(afr[mt], bfr[nt], aff[mt][nt], 0, 0, 0);
    }
    __syncthreads();   // q/k dead; pool becomes vwT | atts

    // ---------------- phase 3: softmax -> atts (stride 56); spill vwT (stride 40) ----------------
    unsigned short* vwT   = pool;                        // [4][64][40] = 10240 shorts
    unsigned short* attsL = pool + 10240 + bat * 2688;   // per-batch [48][56]
#pragma unroll
    for (int mt = 0; mt < 3; mt++) {
#pragma unroll
        for (int r = 0; r < 4; r++) {
            int row = mt * 16 + quad * 4 + r;
            float w[3];
#pragma unroll
            for (int nt = 0; nt < 3; nt++) {
                int col = nt * 16 + l16;
                bool valid = (row < 36) && (col < 36);
                w[nt] = valid ? (aff[mt][nt][r] * 0.125f + exv[mt][r][nt]) : -3.4e38f;
            }
            float mx = fmaxf(fmaxf(w[0], w[1]), w[2]);
#pragma unroll
            for (int d = 1; d < 16; d <<= 1) mx = fmaxf(mx, __shfl_xor(mx, d));
            float e0 = __expf(w[0] - mx), e1 = __expf(w[1] - mx), e2 = __expf(w[2] - mx);
            float s = e0 + e1 + e2;
#pragma unroll
            for (int d = 1; d < 16; d <<= 1) s += __shfl_xor(s, d);
            float rs = 1.0f / s;
            attsL[row * 56 + 0  + l16] = f2bf(e0 * rs);
            attsL[row * 56 + 16 + l16] = f2bf(e1 * rs);
            attsL[row * 56 + 32 + l16] = f2bf(e2 * rs);
        }
    }
    // spill vw section into vwT[batch][e][m] (stride 40; m 0..35 real)
#pragma unroll
    for (int ct = 0; ct < 3; ct++) {
        int g = wave * 48 + ct * 16 + l16;
        int sec = g >> 6, e = g & 63;
        if (sec == 2) {
#pragma unroll
            for (int rt = 0; rt < 9; rt++)
#pragma unroll
                for (int r = 0; r < 4; r++) {
                    int row = rt * 16 + quad * 4 + r;   // 0..143
                    int bb = row / 36, m = row - bb * 36;
                    vwT[bb * 2560 + e * 40 + m] = f2bf(acc[rt][ct][r]);
                }
        }
    }
    __syncthreads();

    // ---------------- phase 4: PV + store ----------------
    const unsigned short* vB = vwT + bat * 2560;
    f32x4 o[3][4] = {};
    {
        bf16x8 pa[3], pb[4], zf = {};
        // ks = 0: m 0..31
#pragma unroll
        for (int mt = 0; mt < 3; mt++) pa[mt] = *(const bf16x8*)&attsL[(mt * 16 + l16) * 56 + quad * 8];
#pragma unroll
        for (int nt = 0; nt < 4; nt++) pb[nt] = *(const bf16x8*)&vB[(nt * 16 + l16) * 40 + quad * 8];
#pragma unroll
        for (int mt = 0; mt < 3; mt++)
#pragma unroll
            for (int nt = 0; nt < 4; nt++)
                o[mt][nt] = __builtin_amdgcn_mfma_f32_16x16x32_bf16(pa[mt], pb[nt], o[mt][nt], 0, 0, 0);
        // ks = 1: m 32..63 (cols 36..47 exact zeros; quads 2,3 zero-frag)
#pragma unroll
        for (int mt = 0; mt < 3; mt++)
            pa[mt] = (quad < 2) ? *(const bf16x8*)&attsL[(mt * 16 + l16) * 56 + 32 + quad * 8] : zf;
#pragma unroll
        for (int nt = 0; nt < 4; nt++)
            pb[nt] = (quad < 2) ? *(const bf16x8*)&vB[(nt * 16 + l16) * 40 + 32 + quad * 8] : zf;
#pragma unroll
        for (int mt = 0; mt < 3; mt++)
#pragma unroll
            for (int nt = 0; nt < 4; nt++)
                o[mt][nt] = __builtin_amdgcn_mfma_f32_16x16x32_bf16(pa[mt], pb[nt], o[mt][nt], 0, 0, 0);
    }

    const size_t obase = (size_t)((bg * 4 + bat) * 36) * DD + h * 64;
#pragma unroll
    for (int mt = 0; mt < 3; mt++)
#pragma unroll
        for (int r = 0; r < 4; r++) {
            int n = mt * 16 + quad * 4 + r;
            if (n < 36) {
#pragma unroll
                for (int nt = 0; nt < 4; nt++)
                    out[obase + (size_t)n * DD + nt * 16 + l16] = o[mt][nt][r] + bo[nt];
            }
        }
}

// ---------------- launcher ----------------
extern "C" void kernel_launch(void* const* d_in, const int* in_sizes, int n_in,
                              void* d_out, int out_size, void* d_ws, size_t ws_size,
                              hipStream_t stream) {
    const float* roi  = (const float*)d_in[0];
    const int*   adj  = (const int*)  d_in[1];
    const float* pe   = (const float*)d_in[2];
    const float* lbl  = (const float*)d_in[3];
    const float* Wq   = (const float*)d_in[4];
    const float* bq   = (const float*)d_in[5];
    const float* Wk   = (const float*)d_in[6];
    const float* bk   = (const float*)d_in[7];
    const float* Wpos = (const float*)d_in[8];
    const float* bpos = (const float*)d_in[9];
    const float* Wout = (const float*)d_in[10];
    const float* bout = (const float*)d_in[11];
    float* out = (float*)d_out;

    char* w = (char*)d_ws;
    unsigned short* roi_bf  = (unsigned short*)(w);               // 9.4 MB
    unsigned short* Wcat_bf = (unsigned short*)(w + 9437184);     // 6.3 MB
    float*          extra   = (float*)(w + 15728640);             // 10.6 MB

    prep_kernel<<<8328, 256, 0, stream>>>(roi, Wq, Wk, Wout, pe, Wpos, bpos, adj, lbl,
                                          roi_bf, Wcat_bf, extra);
    fused_kernel<<<32 * 16, 256, 0, stream>>>(roi_bf, Wcat_bf, bq, bk, extra, bout, out);
}

// Round 12
// 168.913 us; speedup vs baseline: 1.0285x; 1.0285x over previous
//
#include <hip/hip_runtime.h>
#include <hip/hip_bf16.h>

#define BB 128
#define NN 36
#define DD 1024
#define HH 16
#define ROWS (BB*NN)          // 4608

typedef __attribute__((ext_vector_type(8))) __bf16 bf16x8;
typedef __attribute__((ext_vector_type(4))) float f32x4;
typedef __attribute__((ext_vector_type(4))) unsigned short us4;

__device__ inline unsigned short f2bf(float f) {
    __hip_bfloat16 h = __float2bfloat16(f);
    return *reinterpret_cast<unsigned short*>(&h);
}

__device__ inline void async16(const unsigned short* g, unsigned short* l) {
    __builtin_amdgcn_global_load_lds((const __attribute__((address_space(1))) unsigned int*)g,
                                     (__attribute__((address_space(3))) unsigned int*)l, 16, 0, 0);
}

// ---------------- prep: roi->bf16, W->bf16, extra  (one launch) ----------------
// grid: [0,4608) roi cvt | [4608,7680) weight cvt | [7680,8328) extra
__global__ __launch_bounds__(256) void prep_kernel(const float* __restrict__ roi,
                                                   const float* __restrict__ Wq,
                                                   const float* __restrict__ Wk,
                                                   const float* __restrict__ Wout,
                                                   const float* __restrict__ pe,
                                                   const float* __restrict__ Wpos,
                                                   const float* __restrict__ bpos,
                                                   const int* __restrict__ adj,
                                                   const float* __restrict__ lbl,
                                                   unsigned short* __restrict__ roi_bf,
                                                   unsigned short* __restrict__ Wcat_bf,
                                                   float* __restrict__ extra) {
    const int bid = blockIdx.x, tid = threadIdx.x;
    if (bid < 4608) {
        int i = bid * 256 + tid;
        f32x4 v = ((const f32x4*)roi)[i];
        us4 o;
        o.x = f2bf(v[0]); o.y = f2bf(v[1]); o.z = f2bf(v[2]); o.w = f2bf(v[3]);
        ((us4*)roi_bf)[i] = o;
        return;
    }
    if (bid < 7680) {
        int wb = bid - 4608;
        int sel = wb >> 10;
        const float* src = sel == 0 ? Wq : (sel == 1 ? Wk : Wout);
        int i = (wb & 1023) * 256 + tid;
        f32x4 v = ((const f32x4*)src)[i];
        us4 o;
        o.x = f2bf(v[0]); o.y = f2bf(v[1]); o.z = f2bf(v[2]); o.w = f2bf(v[3]);
        ((us4*)(Wcat_bf + (size_t)sel * DD * DD))[i] = o;
        return;
    }
    __shared__ __align__(16) float wps[HH * 64];
    __shared__ float bps[HH];
    for (int i = tid; i < HH * 64; i += 256) wps[i] = Wpos[i];
    if (tid < HH) bps[tid] = bpos[tid];
    __syncthreads();

    int idx = (bid - 7680) * 256 + tid;           // one (b,n,m); 165888 total
    f32x4 pr[16];
    const f32x4* pv = (const f32x4*)(pe + (size_t)idx * 64);
#pragma unroll
    for (int j = 0; j < 16; j++) pr[j] = pv[j];
    int a = adj[idx];
    float add = lbl[idx] + (a > 0 ? 0.f : -9e15f);
    int b = idx / 1296, nm = idx % 1296;
    size_t obase = (size_t)b * (16 * 1296) + nm;
    for (int hh = 0; hh < 16; hh++) {
        const f32x4* wv = (const f32x4*)(wps + hh * 64);
        f32x4 acc4 = {0.f, 0.f, 0.f, 0.f};
#pragma unroll
        for (int j = 0; j < 16; j++) acc4 += pr[j] * wv[j];
        float d = acc4[0] + acc4[1] + acc4[2] + acc4[3] + bps[hh];
        d = fmaxf(d, 0.f);
        d = __logf(fmaxf(d, 1e-6f));
        extra[obase + (size_t)hh * 1296] = d + add;
    }
}

// ---------------- fused GEMM + attention: one block per (4-batch group, head) ----------------
// M=144 (4 batches x 36), N=192 ([q|k|vw] head slices), K=1024, BK=64, XOR-swizzled LDS,
// grid 32x16=512, global_load_lds w16 staging (direct-to-LDS DMA — round 11 showed the
// register-prefetch variant regresses, m133-consistent). This is the m97-class plateau.
__global__ __launch_bounds__(256, 2) void fused_kernel(const unsigned short* __restrict__ A,
                                                       const unsigned short* __restrict__ Wc,
                                                       const float* __restrict__ bq,
                                                       const float* __restrict__ bk,
                                                       const float* __restrict__ extra,
                                                       const float* __restrict__ bout,
                                                       float* __restrict__ out) {
    __shared__ __align__(16) unsigned short pool[21504];   // 43008 B
    const int tid  = threadIdx.x;
    const int wave = tid >> 6, lane = tid & 63;
    const int quad = lane >> 4, l16 = lane & 15;
    const int h  = blockIdx.x & 15;
    const int bg = blockIdx.x >> 4;            // 0..31, 4 batches each
    const int row0 = bg * 144;

    unsigned short* As = pool;                 // [144][64] sw (18 slots x 512)
    unsigned short* Bs = pool + 9216;          // [192][64] sw (24 slots x 512)

    // hoisted staging addresses: slot j = wave + 4*i, i = 0..10 (j<42 valid)
    const unsigned short* gsrc[11];
    unsigned short* ldst[11];
#pragma unroll
    for (int i = 0; i < 11; i++) {
        int j = wave + 4 * i;
        int c = j * 64 + lane;
        if (j < 18) {                          // A: 1152 chunks (144 rows x 8)
            int row = c >> 3;
            int col = ((c & 7) ^ (row & 7)) * 8;
            gsrc[i] = A + (size_t)(row0 + row) * DD + col;
            ldst[i] = As + j * 512;
        } else {                               // B: 1536 chunks (192 rows x 8)
            int cb = c - 1152;
            int row = cb >> 3;
            int sec = row >> 6;
            int wrow = sec * DD + h * 64 + (row & 63);
            int col = ((cb & 7) ^ (row & 7)) * 8;
            gsrc[i] = Wc + (size_t)wrow * DD + col;
            ldst[i] = Bs + (j - 18) * 512;
        }
    }

    f32x4 acc[9][3] = {};                      // rows rt*16, wave's 48-col slice ct*16

#pragma unroll
    for (int k0i = 0; k0i < 16; k0i++) {
#pragma unroll
        for (int i = 0; i < 11; i++) {
            if (i < 10 || wave < 2)
                async16(gsrc[i] + k0i * 64, ldst[i]);
        }
        __syncthreads();

#pragma unroll
        for (int ks = 0; ks < 2; ks++) {
            int kch = ks * 4 + quad;
            bf16x8 bfv[3], afv[9];
#pragma unroll
            for (int ct = 0; ct < 3; ct++) {
                int rowb = wave * 48 + ct * 16 + l16;
                bfv[ct] = *(const bf16x8*)&Bs[rowb * 64 + ((kch ^ (rowb & 7)) * 8)];
            }
#pragma unroll
            for (int rt = 0; rt < 9; rt++) {
                int rowa = rt * 16 + l16;
                afv[rt] = *(const bf16x8*)&As[rowa * 64 + ((kch ^ (rowa & 7)) * 8)];
            }
#pragma unroll
            for (int rt = 0; rt < 9; rt++)
#pragma unroll
                for (int ct = 0; ct < 3; ct++)
                    acc[rt][ct] = __builtin_amdgcn_mfma_f32_16x16x32_bf16(afv[rt], bfv[ct], acc[rt][ct], 0, 0, 0);
        }
        __syncthreads();
    }

    // ---------------- prefetch extra + bout (hidden under spill + QK) ----------------
    const int bat = wave;
    const float* exb = extra + ((size_t)((bg * 4 + bat) * 16 + h)) * 1296;
    float exv[3][4][3];
#pragma unroll
    for (int mt = 0; mt < 3; mt++)
#pragma unroll
        for (int r = 0; r < 4; r++) {
            int row = mt * 16 + quad * 4 + r;
#pragma unroll
            for (int nt = 0; nt < 3; nt++) {
                int col = nt * 16 + l16;
                exv[mt][r][nt] = (row < 36 && col < 36) ? exb[row * 36 + col] : 0.f;
            }
        }
    float bo[4];
#pragma unroll
    for (int nt = 0; nt < 4; nt++) bo[nt] = bout[h * 64 + nt * 16 + l16];

    // ---------------- phase 1: spill q,k (stride 72) ----------------
    unsigned short* qL = pool;                 // [144][72]
    unsigned short* kL = pool + 10368;         // [144][72]
#pragma unroll
    for (int ct = 0; ct < 3; ct++) {
        int g = wave * 48 + ct * 16 + l16;
        int sec = g >> 6, e = g & 63;
        if (sec < 2) {
            unsigned short* dst = (sec == 0) ? qL : kL;
            float bias = (sec == 0) ? bq[h * 64 + e] : bk[h * 64 + e];
#pragma unroll
            for (int rt = 0; rt < 9; rt++)
#pragma unroll
                for (int r = 0; r < 4; r++) {
                    int row = rt * 16 + quad * 4 + r;
                    dst[row * 72 + e] = f2bf(acc[rt][ct][r] + bias);
                }
        }
    }
    __syncthreads();

    // ---------------- phase 2: QK^T per wave (batch = wave) ----------------
    const unsigned short* qB = qL + bat * 36 * 72;
    const unsigned short* kB = kL + bat * 36 * 72;
    int rq[3];
#pragma unroll
    for (int t = 0; t < 3; t++) { int rr = t * 16 + l16; rq[t] = rr < 36 ? rr : 35; }

    f32x4 aff[3][3] = {};
#pragma unroll
    for (int ks = 0; ks < 2; ks++) {
        bf16x8 afr[3], bfr[3];
#pragma unroll
        for (int t = 0; t < 3; t++) afr[t] = *(const bf16x8*)&qB[rq[t] * 72 + ks * 32 + quad * 8];
#pragma unroll
        for (int t = 0; t < 3; t++) bfr[t] = *(const bf16x8*)&kB[rq[t] * 72 + ks * 32 + quad * 8];
#pragma unroll
        for (int mt = 0; mt < 3; mt++)
#pragma unroll
            for (int nt = 0; nt < 3; nt++)
                aff[mt][nt] = __builtin_amdgcn_mfma_f32_16x16x32_bf16(afr[mt], bfr[nt], aff[mt][nt], 0, 0, 0);
    }
    __syncthreads();   // q/k dead; pool becomes vwT | atts

    // ---------------- phase 3: softmax -> atts (stride 56); spill vwT (stride 40) ----------------
    // atts rows 0..47: masked lanes write exact zeros for cols 36..47; rows >=36 are
    // garbage but every consumer discards them -> no explicit zero-fill needed.
    unsigned short* vwT   = pool;                        // [4][64][40] = 10240 shorts
    unsigned short* attsL = pool + 10240 + bat * 2688;   // per-batch [48][56]
#pragma unroll
    for (int mt = 0; mt < 3; mt++) {
#pragma unroll
        for (int r = 0; r < 4; r++) {
            int row = mt * 16 + quad * 4 + r;
            float w[3];
#pragma unroll
            for (int nt = 0; nt < 3; nt++) {
                int col = nt * 16 + l16;
                bool valid = (row < 36) && (col < 36);
                w[nt] = valid ? (aff[mt][nt][r] * 0.125f + exv[mt][r][nt]) : -3.4e38f;
            }
            float mx = fmaxf(fmaxf(w[0], w[1]), w[2]);
#pragma unroll
            for (int d = 1; d < 16; d <<= 1) mx = fmaxf(mx, __shfl_xor(mx, d));
            float e0 = __expf(w[0] - mx), e1 = __expf(w[1] - mx), e2 = __expf(w[2] - mx);
            float s = e0 + e1 + e2;
#pragma unroll
            for (int d = 1; d < 16; d <<= 1) s += __shfl_xor(s, d);
            float rs = 1.0f / s;
            attsL[row * 56 + 0  + l16] = f2bf(e0 * rs);
            attsL[row * 56 + 16 + l16] = f2bf(e1 * rs);
            attsL[row * 56 + 32 + l16] = f2bf(e2 * rs);
        }
    }
    // spill vw section into vwT[batch][e][m] (stride 40; m 0..35 real)
#pragma unroll
    for (int ct = 0; ct < 3; ct++) {
        int g = wave * 48 + ct * 16 + l16;
        int sec = g >> 6, e = g & 63;
        if (sec == 2) {
#pragma unroll
            for (int rt = 0; rt < 9; rt++)
#pragma unroll
                for (int r = 0; r < 4; r++) {
                    int row = rt * 16 + quad * 4 + r;   // 0..143
                    int bb = row / 36, m = row - bb * 36;
                    vwT[bb * 2560 + e * 40 + m] = f2bf(acc[rt][ct][r]);
                }
        }
    }
    __syncthreads();

    // ---------------- phase 4: PV + store ----------------
    // ks=0 reads atts cols 0..31 (real). ks=1: quads 0,1 read cols 32..47 (36..47 exact
    // zeros); quads 2,3 zero-frag. vwT reads beyond m=39 alias next e-row but multiply
    // by zero atts cols.
    const unsigned short* vB = vwT + bat * 2560;
    f32x4 o[3][4] = {};
    {
        bf16x8 pa[3], pb[4], zf = {};
        // ks = 0: m 0..31
#pragma unroll
        for (int mt = 0; mt < 3; mt++) pa[mt] = *(const bf16x8*)&attsL[(mt * 16 + l16) * 56 + quad * 8];
#pragma unroll
        for (int nt = 0; nt < 4; nt++) pb[nt] = *(const bf16x8*)&vB[(nt * 16 + l16) * 40 + quad * 8];
#pragma unroll
        for (int mt = 0; mt < 3; mt++)
#pragma unroll
            for (int nt = 0; nt < 4; nt++)
                o[mt][nt] = __builtin_amdgcn_mfma_f32_16x16x32_bf16(pa[mt], pb[nt], o[mt][nt], 0, 0, 0);
        // ks = 1: m 32..63
#pragma unroll
        for (int mt = 0; mt < 3; mt++)
            pa[mt] = (quad < 2) ? *(const bf16x8*)&attsL[(mt * 16 + l16) * 56 + 32 + quad * 8] : zf;
#pragma unroll
        for (int nt = 0; nt < 4; nt++)
            pb[nt] = (quad < 2) ? *(const bf16x8*)&vB[(nt * 16 + l16) * 40 + 32 + quad * 8] : zf;
#pragma unroll
        for (int mt = 0; mt < 3; mt++)
#pragma unroll
            for (int nt = 0; nt < 4; nt++)
                o[mt][nt] = __builtin_amdgcn_mfma_f32_16x16x32_bf16(pa[mt], pb[nt], o[mt][nt], 0, 0, 0);
    }

    const size_t obase = (size_t)((bg * 4 + bat) * 36) * DD + h * 64;
#pragma unroll
    for (int mt = 0; mt < 3; mt++)
#pragma unroll
        for (int r = 0; r < 4; r++) {
            int n = mt * 16 + quad * 4 + r;
            if (n < 36) {
#pragma unroll
                for (int nt = 0; nt < 4; nt++)
                    out[obase + (size_t)n * DD + nt * 16 + l16] = o[mt][nt][r] + bo[nt];
            }
        }
}

// ---------------- launcher ----------------
extern "C" void kernel_launch(void* const* d_in, const int* in_sizes, int n_in,
                              void* d_out, int out_size, void* d_ws, size_t ws_size,
                              hipStream_t stream) {
    const float* roi  = (const float*)d_in[0];
    const int*   adj  = (const int*)  d_in[1];
    const float* pe   = (const float*)d_in[2];
    const float* lbl  = (const float*)d_in[3];
    const float* Wq   = (const float*)d_in[4];
    const float* bq   = (const float*)d_in[5];
    const float* Wk   = (const float*)d_in[6];
    const float* bk   = (const float*)d_in[7];
    const float* Wpos = (const float*)d_in[8];
    const float* bpos = (const float*)d_in[9];
    const float* Wout = (const float*)d_in[10];
    const float* bout = (const float*)d_in[11];
    float* out = (float*)d_out;

    char* w = (char*)d_ws;
    unsigned short* roi_bf  = (unsigned short*)(w);               // 9.4 MB
    unsigned short* Wcat_bf = (unsigned short*)(w + 9437184);     // 6.3 MB
    float*          extra   = (float*)(w + 15728640);             // 10.6 MB

    prep_kernel<<<8328, 256, 0, stream>>>(roi, Wq, Wk, Wout, pe, Wpos, bpos, adj, lbl,
                                          roi_bf, Wcat_bf, extra);
    fused_kernel<<<32 * 16, 256, 0, stream>>>(roi_bf, Wcat_bf, bq, bk, extra, bout, out);
}